// Round 2
// baseline (295.870 us; speedup 1.0000x reference)
//
#include <hip/hip_runtime.h>
#include <math.h>

#define DD 512
#define HG 64
#define M_ROWS 32768                    // 8*64*64
#define ELEMS ((size_t)M_ROWS * DD)
#define LOG2E 1.44269504088896340736f

typedef __attribute__((ext_vector_type(8))) _Float16 f16x8;
typedef __attribute__((ext_vector_type(2))) _Float16 f16x2;
typedef __attribute__((ext_vector_type(4))) float f32x4;

__device__ __forceinline__ float fexp2_(float x) { return __builtin_amdgcn_exp2f(x); }
__device__ __forceinline__ float frcp_(float x)  { return __builtin_amdgcn_rcpf(x); }
// sigmoid(v) = 1/(1+exp2(-v*log2e)); inf-safe: exp2->inf => rcp->0
__device__ __forceinline__ float fsig_(float v)  { return frcp_(1.0f + fexp2_(-v * LOG2E)); }

// Fused prep: blocks [0,8192) convert x fp32->fp16; blocks [8192,8448)
// transpose+convert the four 512x512 weights into WT (fp16, N-major).
__global__ __launch_bounds__(256) void prep(
    const float* __restrict__ x, _Float16* __restrict__ x16,
    const float* __restrict__ W0, const float* __restrict__ W1,
    const float* __restrict__ W2, const float* __restrict__ W3,
    _Float16* __restrict__ WT)
{
    __shared__ float tile[64][65];
    if (blockIdx.x < 8192) {
        const size_t i = ((size_t)blockIdx.x * 256 + threadIdx.x) * 8;
        const float4 a = *(const float4*)&x[i];
        const float4 b = *(const float4*)&x[i + 4];
        f16x8 h;
        h[0] = (_Float16)a.x; h[1] = (_Float16)a.y;
        h[2] = (_Float16)a.z; h[3] = (_Float16)a.w;
        h[4] = (_Float16)b.x; h[5] = (_Float16)b.y;
        h[6] = (_Float16)b.z; h[7] = (_Float16)b.w;
        *(f16x8*)&x16[i] = h;
        return;
    }
    const int wb = blockIdx.x - 8192;       // 0..255
    const int z = wb >> 6;
    const int rem = wb & 63;
    const int n0 = (rem & 7) * 64, k0 = (rem >> 3) * 64;
    const float* W = (z == 0) ? W0 : (z == 1) ? W1 : (z == 2) ? W2 : W3;
    _Float16* dst = WT + (size_t)z * DD * DD;
    const int t = threadIdx.x;
    const int tr = t >> 6, tc = t & 63;
#pragma unroll
    for (int p = 0; p < 16; ++p)
        tile[p * 4 + tr][tc] = W[(size_t)(k0 + p * 4 + tr) * DD + n0 + tc];
    __syncthreads();
#pragma unroll
    for (int p = 0; p < 16; ++p) {
        const int nn = p * 4 + tr;
        dst[(size_t)(n0 + nn) * DD + k0 + tc] = (_Float16)tile[tc][nn];
    }
}

// fp16 GEMM, 128x128 tile, BK=32, 3-stage LDS pipeline with counted vmcnt
// (loads stay in flight across raw s_barriers; never drained to 0 in loop).
// XOR-swizzled staging: LDS[r][c8] = G[r][c8 ^ ((r>>1)&3)]  (0-conflict).
// MODE 0: A=x16, WT=[W_f|W_in|W_g]^T (N=1536), epilogues dm/u/g (fp16).
// MODE 1: A=v, WT=W_out^T, out f32.
template <int MODE>
__global__ __launch_bounds__(256) void gemm_f16(
    const _Float16* __restrict__ A, const _Float16* __restrict__ WT,
    const float* __restrict__ b0, const float* __restrict__ b1,
    const float* __restrict__ b2, const float* __restrict__ lb_ptr,
    void* __restrict__ o0, void* __restrict__ o1, void* __restrict__ o2)
{
    __shared__ __align__(16) _Float16 As[3][128][32];
    __shared__ __align__(16) _Float16 Bs[3][128][32];

    const int NB = (MODE == 0) ? 12 : 4;
    const int lin = blockIdx.x;
    const int xcd = lin & 7;
    const int n_idx = (lin >> 3) % NB;
    const int mq = lin / (8 * NB);
    const int m0 = (xcd + 8 * mq) * 128;      // same XCD -> same A strip
    const int n0 = n_idx * 128;

    const int tid  = threadIdx.x;
    const int wave = tid >> 6;
    const int lane = tid & 63;
    const int wm = wave >> 1, wn = wave & 1;
    const int lrow = lane & 15;
    const int lk   = lane >> 4;

    // async staging slot: row lane>>2, col8 lane&3; source col8 XOR-swizzled
    const int srow  = lane >> 2;
    const int skoff = ((lane & 3) ^ ((lane >> 3) & 3)) * 8;
    const int ksw   = (lk ^ ((lrow >> 1) & 3)) * 8;

    const _Float16* a_base = A  + (size_t)(m0 + srow) * DD + skoff;
    const _Float16* b_base = WT + (size_t)(n0 + srow) * DD + skoff;

    f32x4 acc[4][4];
#pragma unroll
    for (int i = 0; i < 4; ++i)
#pragma unroll
        for (int j = 0; j < 4; ++j) acc[i][j] = (f32x4)(0.f);

    // 4 global_load_lds per STAGE per thread (2 A + 2 B), 16B each.
#define STAGE(S, KK) do {                                                     \
    _Pragma("unroll")                                                         \
    for (int i_ = 0; i_ < 2; ++i_) {                                          \
        const int row_ = wave * 32 + i_ * 16;                                 \
        __builtin_amdgcn_global_load_lds(                                     \
            (const __attribute__((address_space(1))) void*)                   \
                (b_base + (size_t)row_ * DD + (KK)),                          \
            (__attribute__((address_space(3))) void*)&Bs[S][row_][0], 16, 0, 0); \
        __builtin_amdgcn_global_load_lds(                                     \
            (const __attribute__((address_space(1))) void*)                   \
                (a_base + (size_t)row_ * DD + (KK)),                          \
            (__attribute__((address_space(3))) void*)&As[S][row_][0], 16, 0, 0); \
    } } while (0)

#define COMPUTE(S) do {                                                       \
    f16x8 afr[4], bfr[4];                                                     \
    _Pragma("unroll")                                                         \
    for (int q_ = 0; q_ < 4; ++q_) {                                          \
        afr[q_] = *(const f16x8*)&As[S][wm * 64 + q_ * 16 + lrow][ksw];       \
        bfr[q_] = *(const f16x8*)&Bs[S][wn * 64 + q_ * 16 + lrow][ksw];       \
    }                                                                         \
    __builtin_amdgcn_s_setprio(1);                                            \
    _Pragma("unroll")                                                         \
    for (int mt_ = 0; mt_ < 4; ++mt_)                                         \
        _Pragma("unroll")                                                     \
        for (int nt_ = 0; nt_ < 4; ++nt_)                                     \
            acc[mt_][nt_] = __builtin_amdgcn_mfma_f32_16x16x32_f16(           \
                afr[mt_], bfr[nt_], acc[mt_][nt_], 0, 0, 0);                  \
    __builtin_amdgcn_s_setprio(0);                                            \
    } while (0)

    // prologue: tiles 0,1 in flight (tile t lives in buffer t%3)
    STAGE(0, 0);
    STAGE(1, 32);
    int rs = 0, ws = 2;
    // 16 K-tiles of 32.  Steady state: 8 loads outstanding; vmcnt(4)
    // retires exactly the oldest tile's 4 loads (~2 iterations of cover).
    for (int t = 0; t < 15; ++t) {
        asm volatile("s_waitcnt vmcnt(4)" ::: "memory");
        __builtin_amdgcn_s_barrier();
        if (t < 14) {
            STAGE(ws, (t + 2) * 32);
            ws = (ws == 2) ? 0 : ws + 1;
        }
        COMPUTE(rs);
        rs = (rs == 2) ? 0 : rs + 1;
    }
    asm volatile("s_waitcnt vmcnt(0)" ::: "memory");
    __builtin_amdgcn_s_barrier();
    COMPUTE(rs);
#undef STAGE
#undef COMPUTE

    if (MODE == 0) {
        const int seg = n_idx >> 2;
        const float lbv = lb_ptr[0];
        const float* bias = (seg == 0) ? b0 : (seg == 1) ? b1 : b2;
        _Float16* outp = (seg == 0) ? (_Float16*)o0
                       : (seg == 1) ? (_Float16*)o1 : (_Float16*)o2;
        const int cb = (n_idx & 3) * 128 + wn * 64;
#pragma unroll
        for (int mt = 0; mt < 4; ++mt) {
#pragma unroll
            for (int nt = 0; nt < 4; ++nt) {
                const int col = cb + nt * 16 + lrow;
                const float bcol = bias[col];
#pragma unroll
                for (int r = 0; r < 4; ++r) {
                    const int row = m0 + wm * 64 + mt * 16 + lk * 4 + r;
                    const float v = acc[mt][nt][r] + bcol;
                    float res;
                    if (seg == 0)      res = (1.0f - lbv) * frcp_(1.0f + fexp2_(v * LOG2E));
                    else if (seg == 1) res = v * fsig_(v);
                    else               res = fsig_(v);
                    outp[(size_t)row * DD + col] = (_Float16)res;
                }
            }
        }
    } else {
        float* outp = (float*)o0;
#pragma unroll
        for (int mt = 0; mt < 4; ++mt) {
#pragma unroll
            for (int nt = 0; nt < 4; ++nt) {
                const int col = n0 + wn * 64 + nt * 16 + lrow;
                const float bcol = b0[col];
#pragma unroll
                for (int r = 0; r < 4; ++r) {
                    const int row = m0 + wm * 64 + mt * 16 + lk * 4 + r;
                    outp[(size_t)row * DD + col] = acc[mt][nt][r] + bcol;
                }
            }
        }
    }
}

// Chunk-parallel bidirectional scan. 64-step line split into CH=4 chunks of
// CL=16; linear recurrence => exact carry fix-up via LDS exchange.
// Blocks [0,2048): axis-1 (j) -> ha.  [2048,4096): axis-0 (i) -> hb.
// Each block: one line x 64 d-pairs x 4 chunks (tid = chunk*64 + dpl).
// lam = 1-dm, inp = dm*u; y <- lam*(rot y) + inp; out = fwd + bwd.
#define CH 4
#define CL 16

#define STEP(K, YR0, YI0, YR1, YI1) {                                      \
    const float dm0_ = (float)dmr[K][0], dm1_ = (float)dmr[K][1];          \
    const float lm0_ = 1.0f - dm0_, lm1_ = 1.0f - dm1_;                    \
    float nr_ = fmaf(lm0_, c0 * (YR0) - s0 * (YI0), dm0_ * (float)ur[K][0]); \
    YI0 = lm0_ * (c0 * (YI0) + s0 * (YR0)); YR0 = nr_;                     \
    nr_ = fmaf(lm1_, c1 * (YR1) - s1 * (YI1), dm1_ * (float)ur[K][1]);     \
    YI1 = lm1_ * (c1 * (YI1) + s1 * (YR1)); YR1 = nr_; }

__global__ __launch_bounds__(256, 4) void scan2(
    const _Float16* __restrict__ dm, const _Float16* __restrict__ u,
    const float* __restrict__ theta,
    _Float16* __restrict__ ha, _Float16* __restrict__ hb)
{
    __shared__ float ex[CH][64][13];   // pad 12->13: stride coprime w/ 32 banks

    const int blk  = blockIdx.x & 2047;
    const bool is_i = blockIdx.x >= 2048;
    const int tid   = threadIdx.x;
    const int chunk = tid >> 6;        // 0..3 (wave-uniform)
    const int dpl   = tid & 63;
    const int dpg   = blk & 3;         // 4 groups of 64 d-pairs
    const int line  = blk >> 2;        // 0..511
    const int d0    = (dpg * 64 + dpl) * 2;

    size_t base, stride;
    _Float16* hout;
    if (!is_i) {
        base = (size_t)line * (HG * DD) + d0; stride = DD; hout = ha;
    } else {
        const int bb = line >> 6, j = line & 63;
        base = (size_t)bb * (HG * HG * DD) + (size_t)j * DD + d0;
        stride = (size_t)HG * DD; hout = hb;
    }
    const size_t cbase = base + (size_t)(chunk * CL) * stride;

    float s0, c0, s1, c1;
    sincosf(theta[d0], &s0, &c0);
    sincosf(theta[d0 + 1], &s1, &c1);

    // stage the chunk's dm/u into registers (single global read per element)
    f16x2 dmr[CL], ur[CL];
#pragma unroll
    for (int k = 0; k < CL; ++k) {
        dmr[k] = *(const f16x2*)&dm[cbase + (size_t)k * stride];
        ur[k]  = *(const f16x2*)&u [cbase + (size_t)k * stride];
    }

    // Pass A: zero-init local fwd & bwd scans + decay magnitude product
    float fr0 = 0.f, fi0 = 0.f, fr1 = 0.f, fi1 = 0.f;
    float P0 = 1.f, P1 = 1.f;
#pragma unroll
    for (int k = 0; k < CL; ++k) {
        const float dm0_ = (float)dmr[k][0], dm1_ = (float)dmr[k][1];
        const float lm0_ = 1.0f - dm0_, lm1_ = 1.0f - dm1_;
        P0 *= lm0_; P1 *= lm1_;
        float nr_ = fmaf(lm0_, c0 * fr0 - s0 * fi0, dm0_ * (float)ur[k][0]);
        fi0 = lm0_ * (c0 * fi0 + s0 * fr0); fr0 = nr_;
        nr_ = fmaf(lm1_, c1 * fr1 - s1 * fi1, dm1_ * (float)ur[k][1]);
        fi1 = lm1_ * (c1 * fi1 + s1 * fr1); fr1 = nr_;
    }
    float br0 = 0.f, bi0 = 0.f, br1 = 0.f, bi1 = 0.f;
#pragma unroll
    for (int k = CL - 1; k >= 0; --k) STEP(k, br0, bi0, br1, bi1);

    // chunk decay A = (prod lam) * (c + i s)^CL  (rotation by squaring)
    float rc0 = c0, rs0 = s0, rc1 = c1, rs1 = s1;
#pragma unroll
    for (int q = 0; q < 4; ++q) {     // ^16
        float t0 = rc0 * rc0 - rs0 * rs0; rs0 = 2.f * rc0 * rs0; rc0 = t0;
        float t1 = rc1 * rc1 - rs1 * rs1; rs1 = 2.f * rc1 * rs1; rc1 = t1;
    }

    {
        float* e = ex[chunk][dpl];
        e[0]  = P0 * rc0; e[1]  = P0 * rs0;
        e[2]  = fr0;      e[3]  = fi0;
        e[4]  = br0;      e[5]  = bi0;
        e[6]  = P1 * rc1; e[7]  = P1 * rs1;
        e[8]  = fr1;      e[9]  = fi1;
        e[10] = br1;      e[11] = bi1;
    }
    __syncthreads();

    // fold carries: fwd from chunks < c (left to right), bwd from chunks > c
    float cfr0 = 0.f, cfi0 = 0.f, cfr1 = 0.f, cfi1 = 0.f;
    for (int cc = 0; cc < chunk; ++cc) {
        const float* e = ex[cc][dpl];
        float nr = e[2] + e[0] * cfr0 - e[1] * cfi0;
        cfi0     = e[3] + e[0] * cfi0 + e[1] * cfr0;
        cfr0 = nr;
        nr       = e[8] + e[6] * cfr1 - e[7] * cfi1;
        cfi1     = e[9] + e[6] * cfi1 + e[7] * cfr1;
        cfr1 = nr;
    }
    float cbr0 = 0.f, cbi0 = 0.f, cbr1 = 0.f, cbi1 = 0.f;
    for (int cc = CH - 1; cc > chunk; --cc) {
        const float* e = ex[cc][dpl];
        float nr = e[4] + e[0] * cbr0 - e[1] * cbi0;
        cbi0     = e[5] + e[0] * cbi0 + e[1] * cbr0;
        cbr0 = nr;
        nr       = e[10] + e[6] * cbr1 - e[7] * cbi1;
        cbi1     = e[11] + e[6] * cbi1 + e[7] * cbr1;
        cbr1 = nr;
    }

    // Pass B: re-scan with correct initial state
    float yr0 = cfr0, yi0 = cfi0, yr1 = cfr1, yi1 = cfi1;
    f16x2 fres[CL];
#pragma unroll
    for (int k = 0; k < CL; ++k) {
        STEP(k, yr0, yi0, yr1, yi1);
        f16x2 p; p[0] = (_Float16)yr0; p[1] = (_Float16)yr1;
        fres[k] = p;
    }
    yr0 = cbr0; yi0 = cbi0; yr1 = cbr1; yi1 = cbi1;
#pragma unroll
    for (int k = CL - 1; k >= 0; --k) {
        STEP(k, yr0, yi0, yr1, yi1);
        f16x2 o;
        o[0] = (_Float16)((float)fres[k][0] + yr0);
        o[1] = (_Float16)((float)fres[k][1] + yr1);
        *(f16x2*)&hout[cbase + (size_t)k * stride] = o;
    }
}
#undef STEP

// v = g * (ha+hb) * rsqrt(mean((ha+hb)^2)+1e-6), fp16. One block per row.
__global__ __launch_bounds__(256) void gate_rmsnorm(
    const _Float16* __restrict__ ha, const _Float16* __restrict__ hb,
    const _Float16* __restrict__ g, _Float16* __restrict__ v)
{
    const int row = blockIdx.x;
    const int t = threadIdx.x;
    const size_t b0 = (size_t)row * DD + t * 2;
    const f16x2 a = *(const f16x2*)&ha[b0];
    const f16x2 b = *(const f16x2*)&hb[b0];
    const float h0 = (float)a[0] + (float)b[0];
    const float h1 = (float)a[1] + (float)b[1];
    float ss = h0 * h0 + h1 * h1;
#pragma unroll
    for (int off = 32; off > 0; off >>= 1) ss += __shfl_down(ss, off, 64);
    __shared__ float wsum[4];
    __shared__ float rms_s;
    if ((t & 63) == 0) wsum[t >> 6] = ss;
    __syncthreads();
    if (t == 0) {
        const float tot = wsum[0] + wsum[1] + wsum[2] + wsum[3];
        rms_s = rsqrtf(tot * (1.0f / (float)DD) + 1e-6f);
    }
    __syncthreads();
    const float rms = rms_s;
    const f16x2 gg = *(const f16x2*)&g[b0];
    f16x2 o;
    o[0] = (_Float16)((float)gg[0] * h0 * rms);
    o[1] = (_Float16)((float)gg[1] * h1 * rms);
    *(f16x2*)&v[b0] = o;
}

extern "C" void kernel_launch(void* const* d_in, const int* in_sizes, int n_in,
                              void* d_out, int out_size, void* d_ws, size_t ws_size,
                              hipStream_t stream)
{
    const float* x     = (const float*)d_in[0];
    const float* lb    = (const float*)d_in[1];
    const float* W_in  = (const float*)d_in[2];
    const float* b_in  = (const float*)d_in[3];
    const float* W_f   = (const float*)d_in[4];
    const float* b_f   = (const float*)d_in[5];
    const float* theta = (const float*)d_in[6];
    const float* W_g   = (const float*)d_in[7];
    const float* b_g   = (const float*)d_in[8];
    const float* W_out = (const float*)d_in[9];
    const float* b_out = (const float*)d_in[10];

    float* out = (float*)d_out;
    char* wsb  = (char*)d_ws;

    // ws (98 MB): [0,32M) dm fp16 (later v)  [32M,64M) u fp16
    //             [64M,96M) g fp16           [96M,98M) WT fp16 [2048][512]
    _Float16* dm_v = (_Float16*)wsb;
    _Float16* u_b  = (_Float16*)(wsb + ELEMS * 2);
    _Float16* g_b  = (_Float16*)(wsb + ELEMS * 4);
    _Float16* WT   = (_Float16*)(wsb + ELEMS * 6);
    const size_t WSEG = (size_t)DD * DD;

    // d_out doubles as scratch: [0,32M) ha fp16; [32M,64M) x16, then hb fp16.
    _Float16* ha  = (_Float16*)d_out;
    _Float16* x16 = (_Float16*)((char*)d_out + ELEMS * 2);
    _Float16* hb  = x16;                 // x16 dead after gemm_f16<0>

    prep<<<8448, 256, 0, stream>>>(x, x16, W_f, W_in, W_g, W_out, WT);

    gemm_f16<0><<<3072, 256, 0, stream>>>(x16, WT, b_f, b_in, b_g, lb,
                                          dm_v, u_b, g_b);

    scan2<<<4096, 256, 0, stream>>>(dm_v, u_b, theta, ha, hb);

    // v overwrites dm (dead after scan2)
    gate_rmsnorm<<<M_ROWS, 256, 0, stream>>>(ha, hb, g_b, dm_v);

    // out = v @ W_out^T + b_out  (overwrites all of d_out)
    gemm_f16<1><<<1024, 256, 0, stream>>>(dm_v, WT + 3 * WSEG, b_out, nullptr,
                                          nullptr, nullptr, out, nullptr, nullptr);
}

// Round 3
// 282.989 us; speedup vs baseline: 1.0455x; 1.0455x over previous
//
#include <hip/hip_runtime.h>
#include <math.h>

#define DD 512
#define HG 64
#define M_ROWS 32768                    // 8*64*64
#define ELEMS ((size_t)M_ROWS * DD)
#define LOG2E 1.44269504088896340736f

typedef __attribute__((ext_vector_type(8))) _Float16 f16x8;
typedef __attribute__((ext_vector_type(2))) _Float16 f16x2;
typedef __attribute__((ext_vector_type(4))) float f32x4;

__device__ __forceinline__ float fexp2_(float x) { return __builtin_amdgcn_exp2f(x); }
__device__ __forceinline__ float frcp_(float x)  { return __builtin_amdgcn_rcpf(x); }
// sigmoid(v) = 1/(1+exp2(-v*log2e)); inf-safe: exp2->inf => rcp->0
__device__ __forceinline__ float fsig_(float v)  { return frcp_(1.0f + fexp2_(-v * LOG2E)); }

// Fused prep: blocks [0,8192) convert x fp32->fp16; blocks [8192,8448)
// transpose+convert the four 512x512 weights into WT (fp16, N-major).
__global__ __launch_bounds__(256) void prep(
    const float* __restrict__ x, _Float16* __restrict__ x16,
    const float* __restrict__ W0, const float* __restrict__ W1,
    const float* __restrict__ W2, const float* __restrict__ W3,
    _Float16* __restrict__ WT)
{
    __shared__ float tile[64][65];
    if (blockIdx.x < 8192) {
        const size_t i = ((size_t)blockIdx.x * 256 + threadIdx.x) * 8;
        const float4 a = *(const float4*)&x[i];
        const float4 b = *(const float4*)&x[i + 4];
        f16x8 h;
        h[0] = (_Float16)a.x; h[1] = (_Float16)a.y;
        h[2] = (_Float16)a.z; h[3] = (_Float16)a.w;
        h[4] = (_Float16)b.x; h[5] = (_Float16)b.y;
        h[6] = (_Float16)b.z; h[7] = (_Float16)b.w;
        *(f16x8*)&x16[i] = h;
        return;
    }
    const int wb = blockIdx.x - 8192;       // 0..255
    const int z = wb >> 6;
    const int rem = wb & 63;
    const int n0 = (rem & 7) * 64, k0 = (rem >> 3) * 64;
    const float* W = (z == 0) ? W0 : (z == 1) ? W1 : (z == 2) ? W2 : W3;
    _Float16* dst = WT + (size_t)z * DD * DD;
    const int t = threadIdx.x;
    const int tr = t >> 6, tc = t & 63;
#pragma unroll
    for (int p = 0; p < 16; ++p)
        tile[p * 4 + tr][tc] = W[(size_t)(k0 + p * 4 + tr) * DD + n0 + tc];
    __syncthreads();
#pragma unroll
    for (int p = 0; p < 16; ++p) {
        const int nn = p * 4 + tr;
        dst[(size_t)(n0 + nn) * DD + k0 + tc] = (_Float16)tile[tc][nn];
    }
}

// ---------------------------------------------------------------------------
// 8-phase 256x256 fp16 GEMM (m201-style), BK=64, 8 waves (2M x 4N), 512 thr.
// LDS: A/B double-buffered K-tiles, 128 KB. Half-tile slots recycle at phase
// granularity -> prefetch distance 5-7 phases; vmcnt counted (10), never 0
// in steady state. XOR swizzle chunk^=(row&7) on BOTH stage-src and ds_read.
// Fragment rows: wave wm covers rows wm*64..+63 (half0) and 128+wm*64 (half1)
// so each phase's ds_reads touch exactly one half-tile.
// MODE 0: A=x16, WT=[W_f|W_in|W_g]^T (N=1536), epilogues dm/u/g (fp16).
// MODE 1: A=v, WT=W_out^T (N=512), out f32 + bias.
// ---------------------------------------------------------------------------
template <int MODE>
__global__ __launch_bounds__(512, 2) void gemm8p(
    const _Float16* __restrict__ A, const _Float16* __restrict__ WT,
    const float* __restrict__ b0, const float* __restrict__ b1,
    const float* __restrict__ b2, const float* __restrict__ lb_ptr,
    void* __restrict__ o0, void* __restrict__ o1, void* __restrict__ o2)
{
    __shared__ __align__(16) _Float16 As[2][256][64];
    __shared__ __align__(16) _Float16 Bs[2][256][64];

    const int NB = (MODE == 0) ? 6 : 2;
    const int lin = blockIdx.x;
    const int xcd = lin & 7;
    const int qq  = lin >> 3;
    const int n_idx = qq % NB;
    const int mq  = qq / NB;
    const int m0 = (xcd + 8 * mq) * 256;      // same XCD -> same A strip
    const int n0 = n_idx * 256;

    const int tid  = threadIdx.x;
    const int wv   = tid >> 6;                // 0..7
    const int lane = tid & 63;
    const int wm = wv >> 2, wn = wv & 3;      // 2 x 4 wave grid
    const int lrow = lane & 15;
    const int lk   = lane >> 4;

    // staging constants: wave wv, load j covers rows j*64 + wv*8 + (lane>>3);
    // row&7 == lane>>3, so swizzled source chunk = (lane&7)^(lane>>3).
    const int srow8 = wv * 8 + (lane >> 3);
    const int sswz  = ((lane & 7) ^ (lane >> 3)) * 8;   // in f16 units

    const _Float16* Ag = A  + (size_t)m0 * DD;
    const _Float16* Bg = WT + (size_t)n0 * DD;

    f32x4 acc[8][4];
#pragma unroll
    for (int i = 0; i < 8; ++i)
#pragma unroll
        for (int j = 0; j < 4; ++j) acc[i][j] = (f32x4)(0.f);

#define STG(LDSBUF, GPTR, P_, HALF_, KT_) do {                                 \
    _Pragma("unroll")                                                          \
    for (int j_ = 0; j_ < 2; ++j_) {                                           \
        __builtin_amdgcn_global_load_lds(                                      \
            (const __attribute__((address_space(1))) void*)                    \
              (GPTR + (size_t)((HALF_)*128 + j_*64 + srow8) * DD               \
                     + (KT_)*64 + sswz),                                       \
            (__attribute__((address_space(3))) void*)                          \
              &LDSBUF[P_][(HALF_)*128 + j_*64 + wv*8][0], 16, 0, 0);           \
    } } while (0)

#define LDA(P_, HA_) do {                                                      \
    _Pragma("unroll")                                                          \
    for (int q_ = 0; q_ < 4; ++q_)                                             \
    _Pragma("unroll")                                                          \
    for (int ks_ = 0; ks_ < 2; ++ks_)                                          \
        aA[q_][ks_] = *(const f16x8*)((const char*)&As[P_][0][0]               \
            + (size_t)((wm*64 + q_*16 + (HA_)*128 + lrow) * 128                \
            + (((ks_*4 + lk) ^ (lrow & 7)) * 16)));                            \
    } while (0)

#define LDB(DST_, P_, HB_) do {                                                \
    _Pragma("unroll")                                                          \
    for (int q_ = 0; q_ < 2; ++q_)                                             \
    _Pragma("unroll")                                                          \
    for (int ks_ = 0; ks_ < 2; ++ks_)                                          \
        DST_[q_][ks_] = *(const f16x8*)((const char*)&Bs[P_][0][0]             \
            + (size_t)((wn*32 + q_*16 + (HB_)*128 + lrow) * 128                \
            + (((ks_*4 + lk) ^ (lrow & 7)) * 16)));                            \
    } while (0)

#define MMQ(HA_, BSET_, BOFF_) do {                                            \
    __builtin_amdgcn_s_setprio(1);                                             \
    _Pragma("unroll")                                                          \
    for (int q_ = 0; q_ < 4; ++q_)                                             \
    _Pragma("unroll")                                                          \
    for (int n_ = 0; n_ < 2; ++n_)                                             \
    _Pragma("unroll")                                                          \
    for (int ks_ = 0; ks_ < 2; ++ks_)                                          \
        acc[(HA_)*4 + q_][(BOFF_) + n_] =                                      \
            __builtin_amdgcn_mfma_f32_16x16x32_f16(                            \
                aA[q_][ks_], BSET_[n_][ks_], acc[(HA_)*4 + q_][(BOFF_) + n_],  \
                0, 0, 0);                                                      \
    __builtin_amdgcn_s_setprio(0);                                             \
    } while (0)

#define BAR __builtin_amdgcn_s_barrier()
#define VM(N_) asm volatile("s_waitcnt vmcnt(" #N_ ")" ::: "memory")

    f16x8 aA[4][2], bB0[2][2], bB1[2][2];

    // prologue: tile0 -> buf0 (all 4 half-tiles), tile1 -> buf1 (3 of 4;
    // Ah1(1) staged at P(0,1)).  14 loads; vmcnt(10) retires Ah0(0),Bh0(0)+.
    STG(As, Ag, 0, 0, 0);   // Ah0(0)
    STG(Bs, Bg, 0, 0, 0);   // Bh0(0)
    STG(Bs, Bg, 0, 1, 0);   // Bh1(0)
    STG(As, Ag, 0, 1, 0);   // Ah1(0)
    STG(As, Ag, 1, 0, 1);   // Ah0(1)
    STG(Bs, Bg, 1, 0, 1);   // Bh0(1)
    STG(Bs, Bg, 1, 1, 1);   // Bh1(1)
    VM(10); BAR;

    // steady groups g=0..5 (K-tiles 0..5), staging tiles g+1 (Ah1) and g+2.
    for (int g = 0; g < 6; ++g) {
        const int p = g & 1;
        // P1: reads Ah0(g), Bh0(g); stage Ah1(g+1) into buf p^1
        LDA(p, 0); LDB(bB0, p, 0);
        STG(As, Ag, p ^ 1, 1, g + 1);
        BAR;
        MMQ(0, bB0, 0);
        VM(10); BAR;
        // P2: reads Bh1(g); stage Ah0(g+2) into buf p
        LDB(bB1, p, 1);
        STG(As, Ag, p, 0, g + 2);
        BAR;
        MMQ(0, bB1, 2);
        VM(10); BAR;
        // P3: reads Ah1(g); stage Bh0(g+2)
        LDA(p, 1);
        STG(Bs, Bg, p, 0, g + 2);
        BAR;
        MMQ(1, bB1, 2);
        BAR;
        // P4: no reads; stage Bh1(g+2)
        STG(Bs, Bg, p, 1, g + 2);
        BAR;
        MMQ(1, bB0, 0);
        VM(10); BAR;
    }

    // tail group g=6 (p=0): only Ah1(7) left to stage; exact vmcnt ledger.
    LDA(0, 0); LDB(bB0, 0, 0);
    STG(As, Ag, 1, 1, 7);
    BAR; MMQ(0, bB0, 0); VM(10); BAR;
    LDB(bB1, 0, 1);
    BAR; MMQ(0, bB1, 2); VM(8); BAR;
    LDA(0, 1);
    BAR; MMQ(1, bB1, 2); BAR;
    MMQ(1, bB0, 0);
    VM(4); BAR;

    // tail group g=7 (p=1): no stages; drain ledger 2 -> 0.
    LDA(1, 0); LDB(bB0, 1, 0);
    BAR; MMQ(0, bB0, 0); VM(2); BAR;
    LDB(bB1, 1, 1);
    BAR; MMQ(0, bB1, 2); VM(0); BAR;
    LDA(1, 1);
    BAR; MMQ(1, bB1, 2); BAR;
    MMQ(1, bB0, 0);

#undef STG
#undef LDA
#undef LDB
#undef MMQ
#undef BAR
#undef VM

    // epilogue: row = m0 + wm*64 + (a&3)*16 + (a>>2)*128 + lk*4 + r
    //           col = n0 + wn*32 + (b&1)*16 + (b>>1)*128 + lrow
    if (MODE == 0) {
        const int seg = n_idx >> 1;           // n0 multiples of 256 -> 1 seg
        const float lbv = lb_ptr[0];
        const float* bias = (seg == 0) ? b0 : (seg == 1) ? b1 : b2;
        _Float16* outp = (seg == 0) ? (_Float16*)o0
                       : (seg == 1) ? (_Float16*)o1 : (_Float16*)o2;
        const int cbase = (n_idx & 1) * 256 + wn * 32;
#pragma unroll
        for (int a = 0; a < 8; ++a) {
            const int row = m0 + wm * 64 + (a & 3) * 16 + (a >> 2) * 128 + lk * 4;
#pragma unroll
            for (int b = 0; b < 4; ++b) {
                const int col = cbase + (b & 1) * 16 + (b >> 1) * 128 + lrow;
                const float bcol = bias[col];
#pragma unroll
                for (int r = 0; r < 4; ++r) {
                    const float v = acc[a][b][r] + bcol;
                    float res;
                    if (seg == 0)      res = (1.0f - lbv) * frcp_(1.0f + fexp2_(v * LOG2E));
                    else if (seg == 1) res = v * fsig_(v);
                    else               res = fsig_(v);
                    outp[(size_t)(row + r) * DD + col] = (_Float16)res;
                }
            }
        }
    } else {
        float* outp = (float*)o0;
#pragma unroll
        for (int a = 0; a < 8; ++a) {
            const int row = m0 + wm * 64 + (a & 3) * 16 + (a >> 2) * 128 + lk * 4;
#pragma unroll
            for (int b = 0; b < 4; ++b) {
                const int col = n0 + wn * 32 + (b & 1) * 16 + (b >> 1) * 128 + lrow;
                const float bcol = b0[col];
#pragma unroll
                for (int r = 0; r < 4; ++r)
                    outp[(size_t)(row + r) * DD + col] = acc[a][b][r] + bcol;
            }
        }
    }
}

// Chunk-parallel bidirectional scan. 64-step line split into CH=4 chunks of
// CL=16; linear recurrence => exact carry fix-up via LDS exchange.
// Blocks [0,2048): axis-1 (j) -> ha.  [2048,4096): axis-0 (i) -> hb.
// Each block: one line x 64 d-pairs x 4 chunks (tid = chunk*64 + dpl).
// lam = 1-dm, inp = dm*u; y <- lam*(rot y) + inp; out = fwd + bwd.
#define CH 4
#define CL 16

#define STEP(K, YR0, YI0, YR1, YI1) {                                      \
    const float dm0_ = (float)dmr[K][0], dm1_ = (float)dmr[K][1];          \
    const float lm0_ = 1.0f - dm0_, lm1_ = 1.0f - dm1_;                    \
    float nr_ = fmaf(lm0_, c0 * (YR0) - s0 * (YI0), dm0_ * (float)ur[K][0]); \
    YI0 = lm0_ * (c0 * (YI0) + s0 * (YR0)); YR0 = nr_;                     \
    nr_ = fmaf(lm1_, c1 * (YR1) - s1 * (YI1), dm1_ * (float)ur[K][1]);     \
    YI1 = lm1_ * (c1 * (YI1) + s1 * (YR1)); YR1 = nr_; }

__global__ __launch_bounds__(256, 4) void scan2(
    const _Float16* __restrict__ dm, const _Float16* __restrict__ u,
    const float* __restrict__ theta,
    _Float16* __restrict__ ha, _Float16* __restrict__ hb)
{
    __shared__ float ex[CH][64][13];   // pad 12->13: stride coprime w/ 32 banks

    const int blk  = blockIdx.x & 2047;
    const bool is_i = blockIdx.x >= 2048;
    const int tid   = threadIdx.x;
    const int chunk = tid >> 6;        // 0..3 (wave-uniform)
    const int dpl   = tid & 63;
    const int dpg   = blk & 3;         // 4 groups of 64 d-pairs
    const int line  = blk >> 2;        // 0..511
    const int d0    = (dpg * 64 + dpl) * 2;

    size_t base, stride;
    _Float16* hout;
    if (!is_i) {
        base = (size_t)line * (HG * DD) + d0; stride = DD; hout = ha;
    } else {
        const int bb = line >> 6, j = line & 63;
        base = (size_t)bb * (HG * HG * DD) + (size_t)j * DD + d0;
        stride = (size_t)HG * DD; hout = hb;
    }
    const size_t cbase = base + (size_t)(chunk * CL) * stride;

    float s0, c0, s1, c1;
    sincosf(theta[d0], &s0, &c0);
    sincosf(theta[d0 + 1], &s1, &c1);

    // stage the chunk's dm/u into registers (single global read per element)
    f16x2 dmr[CL], ur[CL];
#pragma unroll
    for (int k = 0; k < CL; ++k) {
        dmr[k] = *(const f16x2*)&dm[cbase + (size_t)k * stride];
        ur[k]  = *(const f16x2*)&u [cbase + (size_t)k * stride];
    }

    // Pass A: zero-init local fwd & bwd scans + decay magnitude product
    float fr0 = 0.f, fi0 = 0.f, fr1 = 0.f, fi1 = 0.f;
    float P0 = 1.f, P1 = 1.f;
#pragma unroll
    for (int k = 0; k < CL; ++k) {
        const float dm0_ = (float)dmr[k][0], dm1_ = (float)dmr[k][1];
        const float lm0_ = 1.0f - dm0_, lm1_ = 1.0f - dm1_;
        P0 *= lm0_; P1 *= lm1_;
        float nr_ = fmaf(lm0_, c0 * fr0 - s0 * fi0, dm0_ * (float)ur[k][0]);
        fi0 = lm0_ * (c0 * fi0 + s0 * fr0); fr0 = nr_;
        nr_ = fmaf(lm1_, c1 * fr1 - s1 * fi1, dm1_ * (float)ur[k][1]);
        fi1 = lm1_ * (c1 * fi1 + s1 * fr1); fr1 = nr_;
    }
    float br0 = 0.f, bi0 = 0.f, br1 = 0.f, bi1 = 0.f;
#pragma unroll
    for (int k = CL - 1; k >= 0; --k) STEP(k, br0, bi0, br1, bi1);

    // chunk decay A = (prod lam) * (c + i s)^CL  (rotation by squaring)
    float rc0 = c0, rs0 = s0, rc1 = c1, rs1 = s1;
#pragma unroll
    for (int q = 0; q < 4; ++q) {     // ^16
        float t0 = rc0 * rc0 - rs0 * rs0; rs0 = 2.f * rc0 * rs0; rc0 = t0;
        float t1 = rc1 * rc1 - rs1 * rs1; rs1 = 2.f * rc1 * rs1; rc1 = t1;
    }

    {
        float* e = ex[chunk][dpl];
        e[0]  = P0 * rc0; e[1]  = P0 * rs0;
        e[2]  = fr0;      e[3]  = fi0;
        e[4]  = br0;      e[5]  = bi0;
        e[6]  = P1 * rc1; e[7]  = P1 * rs1;
        e[8]  = fr1;      e[9]  = fi1;
        e[10] = br1;      e[11] = bi1;
    }
    __syncthreads();

    // fold carries: fwd from chunks < c (left to right), bwd from chunks > c
    float cfr0 = 0.f, cfi0 = 0.f, cfr1 = 0.f, cfi1 = 0.f;
    for (int cc = 0; cc < chunk; ++cc) {
        const float* e = ex[cc][dpl];
        float nr = e[2] + e[0] * cfr0 - e[1] * cfi0;
        cfi0     = e[3] + e[0] * cfi0 + e[1] * cfr0;
        cfr0 = nr;
        nr       = e[8] + e[6] * cfr1 - e[7] * cfi1;
        cfi1     = e[9] + e[6] * cfi1 + e[7] * cfr1;
        cfr1 = nr;
    }
    float cbr0 = 0.f, cbi0 = 0.f, cbr1 = 0.f, cbi1 = 0.f;
    for (int cc = CH - 1; cc > chunk; --cc) {
        const float* e = ex[cc][dpl];
        float nr = e[4] + e[0] * cbr0 - e[1] * cbi0;
        cbi0     = e[5] + e[0] * cbi0 + e[1] * cbr0;
        cbr0 = nr;
        nr       = e[10] + e[6] * cbr1 - e[7] * cbi1;
        cbi1     = e[11] + e[6] * cbi1 + e[7] * cbr1;
        cbr1 = nr;
    }

    // Pass B: re-scan with correct initial state
    float yr0 = cfr0, yi0 = cfi0, yr1 = cfr1, yi1 = cfi1;
    f16x2 fres[CL];
#pragma unroll
    for (int k = 0; k < CL; ++k) {
        STEP(k, yr0, yi0, yr1, yi1);
        f16x2 p; p[0] = (_Float16)yr0; p[1] = (_Float16)yr1;
        fres[k] = p;
    }
    yr0 = cbr0; yi0 = cbi0; yr1 = cbr1; yi1 = cbi1;
#pragma unroll
    for (int k = CL - 1; k >= 0; --k) {
        STEP(k, yr0, yi0, yr1, yi1);
        f16x2 o;
        o[0] = (_Float16)((float)fres[k][0] + yr0);
        o[1] = (_Float16)((float)fres[k][1] + yr1);
        *(f16x2*)&hout[cbase + (size_t)k * stride] = o;
    }
}
#undef STEP

// v = g * (ha+hb) * rsqrt(mean((ha+hb)^2)+1e-6), fp16. One block per row.
__global__ __launch_bounds__(256) void gate_rmsnorm(
    const _Float16* __restrict__ ha, const _Float16* __restrict__ hb,
    const _Float16* __restrict__ g, _Float16* __restrict__ v)
{
    const int row = blockIdx.x;
    const int t = threadIdx.x;
    const size_t b0 = (size_t)row * DD + t * 2;
    const f16x2 a = *(const f16x2*)&ha[b0];
    const f16x2 b = *(const f16x2*)&hb[b0];
    const float h0 = (float)a[0] + (float)b[0];
    const float h1 = (float)a[1] + (float)b[1];
    float ss = h0 * h0 + h1 * h1;
#pragma unroll
    for (int off = 32; off > 0; off >>= 1) ss += __shfl_down(ss, off, 64);
    __shared__ float wsum[4];
    __shared__ float rms_s;
    if ((t & 63) == 0) wsum[t >> 6] = ss;
    __syncthreads();
    if (t == 0) {
        const float tot = wsum[0] + wsum[1] + wsum[2] + wsum[3];
        rms_s = rsqrtf(tot * (1.0f / (float)DD) + 1e-6f);
    }
    __syncthreads();
    const float rms = rms_s;
    const f16x2 gg = *(const f16x2*)&g[b0];
    f16x2 o;
    o[0] = (_Float16)((float)gg[0] * h0 * rms);
    o[1] = (_Float16)((float)gg[1] * h1 * rms);
    *(f16x2*)&v[b0] = o;
}

extern "C" void kernel_launch(void* const* d_in, const int* in_sizes, int n_in,
                              void* d_out, int out_size, void* d_ws, size_t ws_size,
                              hipStream_t stream)
{
    const float* x     = (const float*)d_in[0];
    const float* lb    = (const float*)d_in[1];
    const float* W_in  = (const float*)d_in[2];
    const float* b_in  = (const float*)d_in[3];
    const float* W_f   = (const float*)d_in[4];
    const float* b_f   = (const float*)d_in[5];
    const float* theta = (const float*)d_in[6];
    const float* W_g   = (const float*)d_in[7];
    const float* b_g   = (const float*)d_in[8];
    const float* W_out = (const float*)d_in[9];
    const float* b_out = (const float*)d_in[10];

    float* out = (float*)d_out;
    char* wsb  = (char*)d_ws;

    // ws (98 MB): [0,32M) dm fp16 (later v)  [32M,64M) u fp16
    //             [64M,96M) g fp16           [96M,98M) WT fp16 [2048][512]
    _Float16* dm_v = (_Float16*)wsb;
    _Float16* u_b  = (_Float16*)(wsb + ELEMS * 2);
    _Float16* g_b  = (_Float16*)(wsb + ELEMS * 4);
    _Float16* WT   = (_Float16*)(wsb + ELEMS * 6);
    const size_t WSEG = (size_t)DD * DD;

    // d_out doubles as scratch: [0,32M) ha fp16; [32M,64M) x16, then hb fp16.
    _Float16* ha  = (_Float16*)d_out;
    _Float16* x16 = (_Float16*)((char*)d_out + ELEMS * 2);
    _Float16* hb  = x16;                 // x16 dead after gemm8p<0>

    prep<<<8448, 256, 0, stream>>>(x, x16, W_f, W_in, W_g, W_out, WT);

    gemm8p<0><<<768, 512, 0, stream>>>(x16, WT, b_f, b_in, b_g, lb,
                                       dm_v, u_b, g_b);

    scan2<<<4096, 256, 0, stream>>>(dm_v, u_b, theta, ha, hb);

    // v overwrites dm (dead after scan2)
    gate_rmsnorm<<<M_ROWS, 256, 0, stream>>>(ha, hb, g_b, dm_v);

    // out = v @ W_out^T + b_out  (overwrites all of d_out)
    gemm8p<1><<<256, 512, 0, stream>>>(dm_v, WT + 3 * WSEG, b_out, nullptr,
                                       nullptr, nullptr, out, nullptr, nullptr);
}